// Round 3
// baseline (153.792 us; speedup 1.0000x reference)
//
#include <hip/hip_runtime.h>

// Fused 10-iter screened-Laplace Jacobi, 2048^2 f32.
// Round 2 (resubmit; round-2 bench never acquired a GPU): single-buffer LDS
// (28.7KB -> 4 blocks/CU), direct register staging of all inputs (no LDS
// staging passes), __shfl for x-neighbors, aligned-quad geometry (XHALO=12),
// bijective XCD swizzle.
// Per-iter: read rows into regs -> barrier -> fma+write -> barrier.
// V_new = nsum(V)*R + B with R = mask?0:1/(4+relu(C)), B = mask?bc:0.

#define RES    2048
#define XHALO  12
#define YHALO  10
#define DIMX   128
#define DIMY   56
#define OUTX   (DIMX - 2*XHALO)            // 104
#define OUTY   (DIMY - 2*YHALO)            // 36
#define NBX    ((RES + OUTX - 1) / OUTX)   // 20
#define NBY    ((RES + OUTY - 1) / OUTY)   // 57
#define NWG    (NBX*NBY)                   // 1140
#define NITER  10

__global__ __launch_bounds__(256, 4)
void laplace10_fused(const float* __restrict__ Xin,
                     const float* __restrict__ Cin,
                     const float* __restrict__ BTf,
                     const float* __restrict__ BCin,
                     float* __restrict__ OUT,
                     float* __restrict__ CPOS) {
  __shared__ __align__(16) float V[DIMY][DIMX];   // 28,672 B

  const int t  = threadIdx.x;
  const int q  = t & 31;
  const int ty = t >> 5;
  const int x0 = q * 4;
  const int y0 = ty * 7;

  // bijective XCD swizzle (m204 form; NWG=1140 -> qq=142, rr=4)
  int wg = (int)blockIdx.x;
  {
    const int qq = NWG / 8, rr = NWG % 8;
    const int xcd = wg % 8, off = wg / 8;
    wg = (xcd < rr ? xcd * (qq + 1) : rr * (qq + 1) + (xcd - rr) * qq) + off;
  }
  const int bx  = wg % NBX, by = wg / NBX;
  const int tx0 = bx * OUTX - XHALO;
  const int ty0 = by * OUTY - YHALO;
  const int gx0 = tx0 + x0;                 // always multiple of 4 -> 16B aligned

  const bool xfull = (gx0 >= 0) && (gx0 + 4 <= RES);
  const int  xcl   = (gx0 < 0) ? 0 : (RES - 1);
  const bool xin   = (x0 >= XHALO) && (x0 < XHALO + OUTX) && xfull;

  // quads never straddle the grid edge (gx0 % 4 == 0, RES % 4 == 0)
  auto load4 = [&](const float* __restrict__ g, int row) -> float4 {
    if (xfull) return *(const float4*)(g + (size_t)row * RES + gx0);
    const float v = g[(size_t)row * RES + xcl];
    return make_float4(v, v, v, v);
  };

  // replicate-pad predicates (global edges)
  const bool lq0 = (gx0 + 0 <= 0);
  const bool lq1 = (gx0 + 1 <= 0);
  const bool lq2 = (gx0 + 2 <= 0);
  const bool lq3 = (gx0 + 3 <= 0);
  const bool rq0 = (gx0 + 0 >= RES - 1);
  const bool rq1 = (gx0 + 1 >= RES - 1);
  const bool rq2 = (gx0 + 2 >= RES - 1);
  const bool rq3 = (gx0 + 3 >= RES - 1);

  // ---- direct register staging: mask, B, R (+CPOS store), V0 -> LDS ----
  unsigned mb = 0u;
  float4 Bq[7], Rq[7];
#pragma unroll
  for (int i = 0; i < 7; ++i) {
    const int gr  = ty0 + y0 + i;
    const int gyc = gr < 0 ? 0 : (gr > RES - 1 ? RES - 1 : gr);
    const float4 mv = load4(BTf, gyc);
    const float4 bv = load4(BCin, gyc);
    const unsigned m0 = (__float_as_uint(mv.x) != 0u);
    const unsigned m1 = (__float_as_uint(mv.y) != 0u);
    const unsigned m2 = (__float_as_uint(mv.z) != 0u);
    const unsigned m3 = (__float_as_uint(mv.w) != 0u);
    mb |= (m0 | (m1 << 1) | (m2 << 2) | (m3 << 3)) << (4 * i);
    Bq[i].x = m0 ? bv.x : 0.0f;
    Bq[i].y = m1 ? bv.y : 0.0f;
    Bq[i].z = m2 ? bv.z : 0.0f;
    Bq[i].w = m3 ? bv.w : 0.0f;
  }
#pragma unroll
  for (int i = 0; i < 7; ++i) {
    const int gr  = ty0 + y0 + i;
    const int gyc = gr < 0 ? 0 : (gr > RES - 1 ? RES - 1 : gr);
    const float4 c = load4(Cin, gyc);
    float4 cp;
    cp.x = c.x > 0.0f ? c.x : 0.0f;
    cp.y = c.y > 0.0f ? c.y : 0.0f;
    cp.z = c.z > 0.0f ? c.z : 0.0f;
    cp.w = c.w > 0.0f ? c.w : 0.0f;
    Rq[i].x = (mb >> (4 * i + 0) & 1u) ? 0.0f : 1.0f / (4.0f + cp.x);
    Rq[i].y = (mb >> (4 * i + 1) & 1u) ? 0.0f : 1.0f / (4.0f + cp.y);
    Rq[i].z = (mb >> (4 * i + 2) & 1u) ? 0.0f : 1.0f / (4.0f + cp.z);
    Rq[i].w = (mb >> (4 * i + 3) & 1u) ? 0.0f : 1.0f / (4.0f + cp.w);
    const int yy = y0 + i;
    if (xin && yy >= YHALO && yy < YHALO + OUTY && gr >= 0 && gr < RES) {
      *(float4*)(CPOS + (size_t)gr * RES + gx0) = cp;
    }
  }
#pragma unroll
  for (int i = 0; i < 7; ++i) {
    const int gr  = ty0 + y0 + i;
    const int gyc = gr < 0 ? 0 : (gr > RES - 1 ? RES - 1 : gr);
    const float4 xv = load4(Xin, gyc);
    float4 v0;
    v0.x = (mb >> (4 * i + 0) & 1u) ? Bq[i].x : xv.x;
    v0.y = (mb >> (4 * i + 1) & 1u) ? Bq[i].y : xv.y;
    v0.z = (mb >> (4 * i + 2) & 1u) ? Bq[i].z : xv.z;
    v0.w = (mb >> (4 * i + 3) & 1u) ? Bq[i].w : xv.w;
    *(float4*)(&V[y0 + i][x0]) = v0;
  }
  __syncthreads();

  // neighbor-sum of current LDS state into ns[0..6] (all reads, no writes)
  auto compute_ns = [&](float4* ns) {
    const int ym1 = (y0 == 0) ? 0 : y0 - 1;
    float4 ra = *(const float4*)(&V[ym1][x0]);
    float4 rb = *(const float4*)(&V[y0][x0]);
#pragma unroll
    for (int i = 0; i < 7; ++i) {
      const int yy = y0 + i;
      const int yp = (yy >= DIMY - 1) ? (DIMY - 1) : (yy + 1);
      const float4 rc = *(const float4*)(&V[yp][x0]);
      // x-neighbors via cross-lane shuffle; wrap/half-crossing lanes only
      // feed rim columns outside the validity trapezoid.
      const float lf = __shfl(rb.w, (t + 63) & 63);
      const float rt = __shfl(rb.x, (t + 1) & 63);
      const int g = ty0 + yy;
      const float4 vm = rb;
      const float4 va = (g <= 0) ? vm : ra;        // replicate-pad top
      const float4 vb = (g >= RES - 1) ? vm : rc;  // replicate-pad bottom
      float4 n;
      n.x = va.x + vb.x + (lq0 ? vm.x : lf)   + (rq0 ? vm.x : vm.y);
      n.y = va.y + vb.y + (lq1 ? vm.y : vm.x) + (rq1 ? vm.y : vm.z);
      n.z = va.z + vb.z + (lq2 ? vm.z : vm.y) + (rq2 ? vm.z : vm.w);
      n.w = va.w + vb.w + (lq3 ? vm.w : vm.z) + (rq3 ? vm.w : rt);
      ns[i] = n;
      ra = rb; rb = rc;
    }
  };

  // ---- iterations 1..9: read -> barrier -> fma+write -> barrier ----
#pragma unroll 1
  for (int it = 1; it < NITER; ++it) {
    float4 ns[7];
    compute_ns(ns);
    __syncthreads();
#pragma unroll
    for (int i = 0; i < 7; ++i) {
      const int yy = y0 + i;
      if (yy >= it && yy < DIMY - it) {   // shrinking validity trapezoid
        float4 nv;
        nv.x = fmaf(ns[i].x, Rq[i].x, Bq[i].x);
        nv.y = fmaf(ns[i].y, Rq[i].y, Bq[i].y);
        nv.z = fmaf(ns[i].z, Rq[i].z, Bq[i].z);
        nv.w = fmaf(ns[i].w, Rq[i].w, Bq[i].w);
        *(float4*)(&V[yy][x0]) = nv;
      }
    }
    __syncthreads();
  }

  // ---- iteration 10: compute + clamp epilogue straight to global ----
  {
    float4 ns[7];
    compute_ns(ns);
#pragma unroll
    for (int i = 0; i < 7; ++i) {
      const int yy = y0 + i;
      if (xin && yy >= YHALO && yy < YHALO + OUTY) {
        const int g = ty0 + yy;
        if (g < RES) {
          float4 nv;
          nv.x = fmaf(ns[i].x, Rq[i].x, Bq[i].x);
          nv.y = fmaf(ns[i].y, Rq[i].y, Bq[i].y);
          nv.z = fmaf(ns[i].z, Rq[i].z, Bq[i].z);
          nv.w = fmaf(ns[i].w, Rq[i].w, Bq[i].w);
          float4 o;
          o.x = (nv.x >= 1.0f) ? 0.95f : nv.x;
          o.y = (nv.y >= 1.0f) ? 0.95f : nv.y;
          o.z = (nv.z >= 1.0f) ? 0.95f : nv.z;
          o.w = (nv.w >= 1.0f) ? 0.95f : nv.w;
          *(float4*)(OUT + (size_t)g * RES + gx0) = o;
        }
      }
    }
  }
}

extern "C" void kernel_launch(void* const* d_in, const int* in_sizes, int n_in,
                              void* d_out, int out_size, void* d_ws, size_t ws_size,
                              hipStream_t stream) {
  const float* Xin  = (const float*)d_in[0];
  const float* Cin  = (const float*)d_in[1];
  const float* BTf  = (const float*)d_in[2];   // int bits, nonzero test only
  const float* BCin = (const float*)d_in[3];
  float* OUT  = (float*)d_out;
  float* CPOS = OUT + (size_t)RES * RES;

  hipLaunchKernelGGL(laplace10_fused, dim3(NWG), dim3(256), 0, stream,
                     Xin, Cin, BTf, BCin, OUT, CPOS);
}

// Round 4
// 131.122 us; speedup vs baseline: 1.1729x; 1.1729x over previous
//
#include <hip/hip_runtime.h>

// Fused 10-iter screened-Laplace Jacobi, 2048^2 f32. Round 4.
// Diagnosis r3: VGPR=64 with ~90 live floats -> scratch spills (WRITE_SIZE
// 47MB vs 32MB output, 37us block lifetime). Fix: 512-thread blocks, tile
// 128x64, 4 rows/thread, register-resident rows (cur[4]), LDS dbuf only for
// top/bot halo rows, 1 barrier/iter, no runtime-indexed arrays.
// V_new = nsum(V)*R + B with R = mask?0:1/(4+relu(C)), B = mask?bc:0.

#define RES    2048
#define XHALO  12
#define YHALO  10
#define DIMX   128
#define DIMY   64
#define OUTX   (DIMX - 2*XHALO)            // 104
#define OUTY   (DIMY - 2*YHALO)            // 44
#define NBX    ((RES + OUTX - 1) / OUTX)   // 20
#define NBY    ((RES + OUTY - 1) / OUTY)   // 47
#define NWG    (NBX*NBY)                   // 940
#define NITER  10

__global__ __launch_bounds__(512, 4)
void laplace10_fused(const float* __restrict__ Xin,
                     const float* __restrict__ Cin,
                     const float* __restrict__ BTf,
                     const float* __restrict__ BCin,
                     float* __restrict__ OUT,
                     float* __restrict__ CPOS) {
  __shared__ __align__(16) float V[2][DIMY][DIMX];   // 65,536 B -> 2 blocks/CU

  const int t  = threadIdx.x;
  const int q  = t & 31;
  const int ty = t >> 5;          // 0..15
  const int x0 = q * 4;
  const int y0 = ty * 4;          // rows y0..y0+3

  // bijective XCD swizzle (NWG=940: qq=117, rr=4)
  int wg = (int)blockIdx.x;
  {
    const int qq = NWG / 8, rr = NWG % 8;
    const int xcd = wg % 8, off = wg / 8;
    wg = (xcd < rr ? xcd * (qq + 1) : rr * (qq + 1) + (xcd - rr) * qq) + off;
  }
  const int bx  = wg % NBX, by = wg / NBX;
  const int tx0 = bx * OUTX - XHALO;
  const int ty0 = by * OUTY - YHALO;
  const int gx0 = tx0 + x0;                 // multiple of 4 -> 16B aligned

  const bool xfull = (gx0 >= 0) && (gx0 + 4 <= RES);
  const int  xcl   = (gx0 < 0) ? 0 : (RES - 1);
  const bool xin   = xfull && (x0 >= XHALO) && (x0 < XHALO + OUTX);

  auto load4 = [&](const float* __restrict__ g, int row) -> float4 {
    if (xfull) return *(const float4*)(g + (size_t)row * RES + gx0);
    const float v = g[(size_t)row * RES + xcl];
    return make_float4(v, v, v, v);
  };

  // replicate-pad walls (global edges); per-lane bools -> sgpr masks
  const bool lq0 = (gx0 + 0 <= 0);
  const bool lq1 = (gx0 + 1 <= 0);
  const bool lq2 = (gx0 + 2 <= 0);
  const bool lq3 = (gx0 + 3 <= 0);
  const bool rq0 = (gx0 + 0 >= RES - 1);
  const bool rq1 = (gx0 + 1 >= RES - 1);
  const bool rq2 = (gx0 + 2 >= RES - 1);
  const bool rq3 = (gx0 + 3 >= RES - 1);

  // ---- staging: mask/B/R (+CPOS), V0 -> regs (cur) + LDS buf0 ----
  unsigned mb = 0u;
  float4 Bq[4], Rq[4], cur[4];
#pragma unroll
  for (int j = 0; j < 4; ++j) {
    const int yy = y0 + j;
    const int g  = ty0 + yy;
    const int gc = g < 0 ? 0 : (g > RES - 1 ? RES - 1 : g);
    const float4 mv = load4(BTf, gc);
    const float4 bv = load4(BCin, gc);
    const float4 cv = load4(Cin, gc);
    const float4 xv = load4(Xin, gc);
    const unsigned m0 = (__float_as_uint(mv.x) != 0u);
    const unsigned m1 = (__float_as_uint(mv.y) != 0u);
    const unsigned m2 = (__float_as_uint(mv.z) != 0u);
    const unsigned m3 = (__float_as_uint(mv.w) != 0u);
    mb |= (m0 | (m1 << 1) | (m2 << 2) | (m3 << 3)) << (4 * j);
    float4 B;
    B.x = m0 ? bv.x : 0.0f;  B.y = m1 ? bv.y : 0.0f;
    B.z = m2 ? bv.z : 0.0f;  B.w = m3 ? bv.w : 0.0f;
    Bq[j] = B;
    float4 cp;
    cp.x = cv.x > 0.0f ? cv.x : 0.0f;
    cp.y = cv.y > 0.0f ? cv.y : 0.0f;
    cp.z = cv.z > 0.0f ? cv.z : 0.0f;
    cp.w = cv.w > 0.0f ? cv.w : 0.0f;
    float4 R;
    R.x = m0 ? 0.0f : 1.0f / (4.0f + cp.x);
    R.y = m1 ? 0.0f : 1.0f / (4.0f + cp.y);
    R.z = m2 ? 0.0f : 1.0f / (4.0f + cp.z);
    R.w = m3 ? 0.0f : 1.0f / (4.0f + cp.w);
    Rq[j] = R;
    float4 v0;
    v0.x = m0 ? B.x : xv.x;  v0.y = m1 ? B.y : xv.y;
    v0.z = m2 ? B.z : xv.z;  v0.w = m3 ? B.w : xv.w;
    cur[j] = v0;
    *(float4*)(&V[0][yy][x0]) = v0;
    if (xin && yy >= YHALO && yy < YHALO + OUTY && g < RES) {
      *(float4*)(CPOS + (size_t)g * RES + gx0) = cp;
    }
  }
  __syncthreads();

  const int ytop = (ty == 0)  ? 0        : y0 - 1;   // clamped; rim-garbage ok
  const int ybot = (ty == 15) ? DIMY - 1 : y0 + 4;

  // one Jacobi row-update: vp=row above (old), vm=this row (old), vn=row below (old)
  #define ROW_STEP(J, VP, VM, VN, NV)                                          \
    {                                                                          \
      const int g_ = ty0 + y0 + (J);                                           \
      const float lf = __shfl((VM).w, (t + 63) & 63);                          \
      const float rt = __shfl((VM).x, (t + 1) & 63);                           \
      const float4 va = (g_ <= 0)       ? (VM) : (VP);                         \
      const float4 vb = (g_ >= RES - 1) ? (VM) : (VN);                         \
      const float n0 = va.x + vb.x + (lq0 ? (VM).x : lf)     + (rq0 ? (VM).x : (VM).y); \
      const float n1 = va.y + vb.y + (lq1 ? (VM).y : (VM).x) + (rq1 ? (VM).y : (VM).z); \
      const float n2 = va.z + vb.z + (lq2 ? (VM).z : (VM).y) + (rq2 ? (VM).z : (VM).w); \
      const float n3 = va.w + vb.w + (lq3 ? (VM).w : (VM).z) + (rq3 ? (VM).w : rt);     \
      (NV).x = fmaf(n0, Rq[J].x, Bq[J].x);                                     \
      (NV).y = fmaf(n1, Rq[J].y, Bq[J].y);                                     \
      (NV).z = fmaf(n2, Rq[J].z, Bq[J].z);                                     \
      (NV).w = fmaf(n3, Rq[J].w, Bq[J].w);                                     \
    }

  // ---- iterations 1..9: read top/bot halo from src, write 4 rows to dst ----
#pragma unroll 1
  for (int it = 1; it < NITER; ++it) {
    const float* const src = &V[(it + 1) & 1][0][0];
    float* const dst       = &V[it & 1][0][0];
    const float4 top = *(const float4*)(src + ytop * DIMX + x0);
    const float4 bot = *(const float4*)(src + ybot * DIMX + x0);
    float4 n0v, n1v, n2v, n3v;
    ROW_STEP(0, top,    cur[0], cur[1], n0v);
    ROW_STEP(1, cur[0], cur[1], cur[2], n1v);
    ROW_STEP(2, cur[1], cur[2], cur[3], n2v);
    ROW_STEP(3, cur[2], cur[3], bot,    n3v);
    cur[0] = n0v; cur[1] = n1v; cur[2] = n2v; cur[3] = n3v;
    *(float4*)(dst + (y0 + 0) * DIMX + x0) = n0v;
    *(float4*)(dst + (y0 + 1) * DIMX + x0) = n1v;
    *(float4*)(dst + (y0 + 2) * DIMX + x0) = n2v;
    *(float4*)(dst + (y0 + 3) * DIMX + x0) = n3v;
    __syncthreads();
  }

  // ---- iteration 10: compute + clamp epilogue straight from registers ----
  {
    const float* const src = &V[1][0][0];   // iter 9 wrote buf[9&1]=buf[1]
    const float4 top = *(const float4*)(src + ytop * DIMX + x0);
    const float4 bot = *(const float4*)(src + ybot * DIMX + x0);
    float4 n0v, n1v, n2v, n3v;
    ROW_STEP(0, top,    cur[0], cur[1], n0v);
    ROW_STEP(1, cur[0], cur[1], cur[2], n1v);
    ROW_STEP(2, cur[1], cur[2], cur[3], n2v);
    ROW_STEP(3, cur[2], cur[3], bot,    n3v);
    cur[0] = n0v; cur[1] = n1v; cur[2] = n2v; cur[3] = n3v;
#pragma unroll
    for (int j = 0; j < 4; ++j) {
      const int yy = y0 + j;
      const int g  = ty0 + yy;
      if (xin && yy >= YHALO && yy < YHALO + OUTY && g < RES) {
        const float4 nv = cur[j];
        float4 o;
        o.x = (nv.x >= 1.0f) ? 0.95f : nv.x;
        o.y = (nv.y >= 1.0f) ? 0.95f : nv.y;
        o.z = (nv.z >= 1.0f) ? 0.95f : nv.z;
        o.w = (nv.w >= 1.0f) ? 0.95f : nv.w;
        *(float4*)(OUT + (size_t)g * RES + gx0) = o;
      }
    }
  }
  #undef ROW_STEP
}

extern "C" void kernel_launch(void* const* d_in, const int* in_sizes, int n_in,
                              void* d_out, int out_size, void* d_ws, size_t ws_size,
                              hipStream_t stream) {
  const float* Xin  = (const float*)d_in[0];
  const float* Cin  = (const float*)d_in[1];
  const float* BTf  = (const float*)d_in[2];   // int32 bits, nonzero test only
  const float* BCin = (const float*)d_in[3];
  float* OUT  = (float*)d_out;
  float* CPOS = OUT + (size_t)RES * RES;

  hipLaunchKernelGGL(laplace10_fused, dim3(NWG), dim3(512), 0, stream,
                     Xin, Cin, BTf, BCin, OUT, CPOS);
}